// Round 13
// baseline (5376.981 us; speedup 1.0000x reference)
//
#include <hip/hip_runtime.h>
#include <hip/hip_bf16.h>

#define SEQ   512
#define BATCH 128
#define VOCAB 30000
#define EDIM  256
#define HDIM  256
#define NT    9

// ---------------- K0b: detect mask storage dtype ----------------
__global__ void k_detect(const unsigned char* __restrict__ m, int* __restrict__ flag) {
    __shared__ int ok_sh;
    if (threadIdx.x == 0) ok_sh = 1;
    __syncthreads();
    int b = threadIdx.x;  // 128 threads, one row each
    const uint4* row = (const uint4*)(m + b * SEQ);
    int ok = 1, prev = 1;
    for (int i = 0; i < SEQ / 16; ++i) {
        uint4 v = row[i];
        unsigned w[4] = {v.x, v.y, v.z, v.w};
        #pragma unroll
        for (int wi = 0; wi < 4; ++wi) {
            #pragma unroll
            for (int j = 0; j < 4; ++j) {
                int byte = (w[wi] >> (8 * j)) & 255;
                if (byte > 1 || byte > prev) ok = 0;
                prev = byte;
            }
        }
    }
    if (!ok) atomicAnd(&ok_sh, 0);
    __syncthreads();
    if (threadIdx.x == 0) *flag = ok_sh;
}

// ---------------- K1: table[v][n] = embed[v] . Wcat[n] + bias[n] ----------------
__global__ __launch_bounds__(256) void k_table_gemm(
    const float* __restrict__ emb, const float* __restrict__ Wf,
    const float* __restrict__ Wb, const float* __restrict__ bf,
    const float* __restrict__ bb, float* __restrict__ table) {
    __shared__ __align__(16) float As[64][68];  // [k][m]
    __shared__ __align__(16) float Bs[64][68];  // [k][n]
    int t  = threadIdx.x;
    int tx = t & 15, ty = t >> 4;
    int n0 = blockIdx.x * 64;
    int v0 = blockIdx.y * 64;
    float acc[4][4] = {};
    for (int kc = 0; kc < 4; ++kc) {
        #pragma unroll
        for (int rr = 0; rr < 4; ++rr) {
            int slot = t + rr * 256;
            int m = slot >> 4, kq = slot & 15;
            int v = v0 + m;
            float4 a = (v < VOCAB)
                ? *(const float4*)&emb[v * EDIM + kc * 64 + kq * 4]
                : make_float4(0.f, 0.f, 0.f, 0.f);
            As[kq * 4 + 0][m] = a.x; As[kq * 4 + 1][m] = a.y;
            As[kq * 4 + 2][m] = a.z; As[kq * 4 + 3][m] = a.w;
            int n = n0 + m;
            const float* Wrow = (n < 1024) ? &Wf[n * 256] : &Wb[(n - 1024) * 256];
            float4 bvec = *(const float4*)&Wrow[kc * 64 + kq * 4];
            Bs[kq * 4 + 0][m] = bvec.x; Bs[kq * 4 + 1][m] = bvec.y;
            Bs[kq * 4 + 2][m] = bvec.z; Bs[kq * 4 + 3][m] = bvec.w;
        }
        __syncthreads();
        #pragma unroll
        for (int k = 0; k < 64; ++k) {
            float4 a = *(const float4*)&As[k][ty * 4];
            float4 b = *(const float4*)&Bs[k][tx * 4];
            acc[0][0] += a.x * b.x; acc[0][1] += a.x * b.y; acc[0][2] += a.x * b.z; acc[0][3] += a.x * b.w;
            acc[1][0] += a.y * b.x; acc[1][1] += a.y * b.y; acc[1][2] += a.y * b.z; acc[1][3] += a.y * b.w;
            acc[2][0] += a.z * b.x; acc[2][1] += a.z * b.y; acc[2][2] += a.z * b.z; acc[2][3] += a.z * b.w;
            acc[3][0] += a.w * b.x; acc[3][1] += a.w * b.y; acc[3][2] += a.w * b.z; acc[3][3] += a.w * b.w;
        }
        __syncthreads();
    }
    int n = n0 + tx * 4;
    const float* bi = (n < 1024) ? &bf[n] : &bb[n - 1024];
    float4 bias = *(const float4*)bi;
    #pragma unroll
    for (int i = 0; i < 4; ++i) {
        int v = v0 + ty * 4 + i;
        if (v < VOCAB) {
            float4 o;
            o.x = acc[i][0] + bias.x; o.y = acc[i][1] + bias.y;
            o.z = acc[i][2] + bias.z; o.w = acc[i][3] + bias.w;
            *(float4*)&table[(size_t)v * 2048 + n] = o;
        }
    }
}

// ---------------- K2: clustered LSTM, fused dot->nonlin->publish -------------
// 256 blocks x 1024 threads. cluster = bid>>3, myb = bid&7; dir = cluster&1.
// Group g = t>>5 owns the 4 gate-rows of dim g: local rows {g,32+g,64+g,96+g}
// (same staging map as r12: lr = q*32+g <-> global row q*256+myb*32+g).
// Dot: lane kc = t&31 reads k4 in {kc, kc+32}; contiguous 256B/16-lane phases.
// Butterfly (r12-proven): lane kc ends with gate sum for tile m = bitrev5(kc)
// = (gate q = m>>3, batch b = m&7). Lane adds its own xg, then shfl_xor(1,2,3)
// gathers all 4 gates into each quad lane; nonlin computed replicated; quad
// leader (kc&3==0) writes h to h_cur[wb] (pad 260 -> conflict-free) and hx.
// h_cur double-buffered: dot+emission read rb = it&1, writers/copy fill wb.
// ONE barrier per step. Exchange protocol identical to r9-r12 (relaxed agent
// atomics -> L3, per-wave vmcnt(0), LDS ctr (16 waves) -> t0 publishes
// monotonic tag, 2-slot ring; waves 8-15 poll+copy per-peer; waves 4-7 emit).
__global__ __launch_bounds__(1024) void k_lstm_cl(
    const int* __restrict__ ids, const float* __restrict__ Whhf,
    const float* __restrict__ Whhb, const float* __restrict__ table,
    const float* __restrict__ Wout, float* __restrict__ emp,
    float* hx, int* tagbuf) {
    extern __shared__ float sh_w[];            // [128][256] linear = 128 KB
    __shared__ float h_cur[2][8][260];         // 16.6 KB double-buffered
    __shared__ float wout_s[NT][257];
    __shared__ int   sh_ctr;

    const int t   = threadIdx.x;
    const int bid = blockIdx.x;
    const int cluster = bid >> 3;
    const int myb = bid & 7;
    const int dir = cluster & 1;
    const int oct = cluster >> 1;
    const int gbatch = oct * 8 + myb;
    const int dirOff = dir * 1024;

    const int lane = t & 63;
    const int wv   = t >> 6;
    const int g    = t >> 5;                   // dim group 0..31
    const int kc   = t & 31;                   // k lane

    // tile identity after butterfly: m = bitrev5(kc) -> gate q, batch bq
    const int mfin = ((kc & 1) << 4) | ((kc & 2) << 2) | (kc & 4)
                   | ((kc & 8) >> 2) | ((kc & 16) >> 4);
    const int q  = mfin >> 3;
    const int bq = mfin & 7;
    const int sel = kc & 3;
    const bool writer = (sel == 0);
    const int xcol = q * 256 + myb * 32 + g;   // xg column for this lane
    const int grow_ids = (oct * 8 + bq) * SEQ; // ids row base for this lane

    const int em = t - 256;                    // emission map (waves 4-7)
    const int etg = em >> 4, el = em & 15;
    const int cw = wv - 8;                     // copy-wave peer id (waves 8-15)

    const float* Whh = dir ? Whhb : Whhf;

    if (t == 0) sh_ctr = 0;
    for (int idx = t; idx < NT * 256; idx += 1024)
        wout_s[idx >> 8][idx & 255] = Wout[(idx >> 8) * 512 + dir * 256 + (idx & 255)];
    // stage W-slice (linear): local row lr = q*32+g <-> global q*256+myb*32+g
    {
        int lr = t >> 3, seg = t & 7;
        int grow = (lr >> 5) * 256 + myb * 32 + (lr & 31);
        const float4* src = (const float4*)(Whh + (size_t)grow * 256) + seg * 8;
        float4* dst = (float4*)(sh_w + lr * 256) + seg * 8;
        #pragma unroll
        for (int i = 0; i < 8; ++i) dst[i] = src[i];
    }
    for (int idx = t; idx < 2048; idx += 1024)
        h_cur[0][idx >> 8][idx & 255] = 0.f;
    float c_state = 0.f;
    __syncthreads();

    // xg prefetch for it=0 (per-lane single float: own gate/dim/batch)
    float xg;
    {
        int s0 = dir ? SEQ - 1 : 0;
        int id = ids[grow_ids + s0];
        xg = table[(size_t)id * 2048 + dirOff + xcol];
    }

    const float* w0p = sh_w + g * 256 + 4 * kc;          // row g      (gate i)
    const float* w1p = w0p + 32 * 256;                   // row 32+g   (gate f)
    const float* w2p = w0p + 64 * 256;                   // row 64+g   (gate g)
    const float* w3p = w0p + 96 * 256;                   // row 96+g   (gate o)

    #pragma unroll 1
    for (int it = 0; it < SEQ; ++it) {
        const int rb = it & 1, wb = rb ^ 1;
        const float* hb = &h_cur[rb][0][0] + 4 * kc;

        float a[32];
        #pragma unroll
        for (int m = 0; m < 32; ++m) a[m] = 0.f;
        #pragma unroll
        for (int j = 0; j < 2; ++j) {
            float4 w0 = *(const float4*)(w0p + 128 * j);
            float4 w1 = *(const float4*)(w1p + 128 * j);
            float4 w2 = *(const float4*)(w2p + 128 * j);
            float4 w3 = *(const float4*)(w3p + 128 * j);
            #pragma unroll
            for (int b = 0; b < 8; ++b) {
                float4 hv = *(const float4*)(hb + b * 260 + 128 * j);
                a[0  + b] += w0.x*hv.x + w0.y*hv.y + w0.z*hv.z + w0.w*hv.w;
                a[8  + b] += w1.x*hv.x + w1.y*hv.y + w1.z*hv.z + w1.w*hv.w;
                a[16 + b] += w2.x*hv.x + w2.y*hv.y + w2.z*hv.z + w2.w*hv.w;
                a[24 + b] += w3.x*hv.x + w3.y*hv.y + w3.z*hv.z + w3.w*hv.w;
            }
        }
        // 5-stage thinning butterfly (r12-proven)
        #pragma unroll
        for (int m = 0; m < 16; ++m) {
            int bit = kc & 1;
            float sent = bit ? a[m] : a[m + 16];
            float recv = __shfl_xor(sent, 1);
            a[m] = (bit ? a[m + 16] : a[m]) + recv;
        }
        #pragma unroll
        for (int m = 0; m < 8; ++m) {
            int bit = kc & 2;
            float sent = bit ? a[m] : a[m + 8];
            float recv = __shfl_xor(sent, 2);
            a[m] = (bit ? a[m + 8] : a[m]) + recv;
        }
        #pragma unroll
        for (int m = 0; m < 4; ++m) {
            int bit = kc & 4;
            float sent = bit ? a[m] : a[m + 4];
            float recv = __shfl_xor(sent, 4);
            a[m] = (bit ? a[m + 4] : a[m]) + recv;
        }
        #pragma unroll
        for (int m = 0; m < 2; ++m) {
            int bit = kc & 8;
            float sent = bit ? a[m] : a[m + 2];
            float recv = __shfl_xor(sent, 8);
            a[m] = (bit ? a[m + 2] : a[m]) + recv;
        }
        {
            int bit = kc & 16;
            float sent = bit ? a[0] : a[1];
            float recv = __shfl_xor(sent, 16);
            a[0] = (bit ? a[1] : a[0]) + recv;
        }

        // gather 4 gates into every quad lane; each lane pre-added its own xg
        float v  = a[0] + xg;
        float x1 = __shfl_xor(v, 1);   // partner gate q^2
        float x2 = __shfl_xor(v, 2);   // partner gate q^1
        float x3 = __shfl_xor(v, 3);   // partner gate q^3
        float iv = (sel == 0) ? v  : (sel == 1) ? x1 : (sel == 2) ? x2 : x3;
        float fv = (sel == 0) ? x2 : (sel == 1) ? x3 : (sel == 2) ? v  : x1;
        float gv = (sel == 0) ? x1 : (sel == 1) ? v  : (sel == 2) ? x3 : x2;
        float ov = (sel == 0) ? x3 : (sel == 1) ? x2 : (sel == 2) ? x1 : v;

        float si = 1.f / (1.f + expf(-iv));
        float sf = 1.f / (1.f + expf(-fv));
        float so = 1.f / (1.f + expf(-ov));
        float tg = tanhf(gv);
        c_state = sf * c_state + si * tg;
        float hh = so * tanhf(c_state);

        const int p = it & 1;
        float* hxp = hx + (size_t)p * 65536 + (size_t)cluster * 2048;
        int* tags = tagbuf + p * 256 + cluster * 8;

        if (writer) {
            h_cur[wb][bq][myb * 32 + g] = hh;
            __hip_atomic_store(&hxp[bq * 256 + myb * 32 + g], hh,
                               __ATOMIC_RELAXED, __HIP_MEMORY_SCOPE_AGENT);
        }
        asm volatile("s_waitcnt vmcnt(0)" ::: "memory");
        if (lane == 0) atomicAdd(&sh_ctr, 1);
        if (t == 0) {
            while (__hip_atomic_load(&sh_ctr, __ATOMIC_RELAXED,
                                     __HIP_MEMORY_SCOPE_WORKGROUP) < 16 * (it + 1)) {}
            __hip_atomic_store(&tags[myb], it,
                               __ATOMIC_RELAXED, __HIP_MEMORY_SCOPE_AGENT);
        }

        // xg prefetch for it+1 (all lanes; consumed next iteration)
        if (it < SEQ - 1) {
            int sn = dir ? (SEQ - 2 - it) : (it + 1);
            int id = ids[grow_ids + sn];
            xg = table[(size_t)id * 2048 + dirOff + xcol];
        }

        if (wv >= 8) {
            // per-peer poll + copy into h_cur[wb]
            int j = cw;
            if (j != myb) {
                while (__hip_atomic_load(&tags[j], __ATOMIC_RELAXED,
                                         __HIP_MEMORY_SCOPE_AGENT) != it)
                    __builtin_amdgcn_s_sleep(1);
                #pragma unroll
                for (int rep = 0; rep < 4; ++rep) {
                    int idx = rep * 64 + lane;
                    int nb2 = idx >> 5, nd2 = idx & 31;
                    float vv = __hip_atomic_load(&hxp[nb2 * 256 + j * 32 + nd2],
                                                 __ATOMIC_RELAXED, __HIP_MEMORY_SCOPE_AGENT);
                    h_cur[wb][nb2][j * 32 + nd2] = vv;
                }
            }
        } else if (wv >= 4) {
            // emission for h_{it-1} (lives in h_cur[rb]; no writer touches rb)
            if (it > 0 && em < 144) {
                int sp = dir ? (SEQ - it) : (it - 1);
                float pe = 0.f;
                #pragma unroll
                for (int j = 0; j < 16; ++j)
                    pe += wout_s[etg][el + 16 * j] * h_cur[rb][myb][el + 16 * j];
                pe += __shfl_xor(pe, 1); pe += __shfl_xor(pe, 2);
                pe += __shfl_xor(pe, 4); pe += __shfl_xor(pe, 8);
                if (el == 0)
                    emp[(((size_t)(dir * BATCH) + gbatch) * SEQ + sp) * NT + etg] = pe;
            }
        }
        __syncthreads();   // single barrier: h_cur[wb] complete, rb free
    }

    // final emission for h_{511} (in h_cur[SEQ&1 == 0])
    if (t < 144) {
        int etg2 = t >> 4, el2 = t & 15;
        int sp = dir ? 0 : (SEQ - 1);
        float pe = 0.f;
        #pragma unroll
        for (int j = 0; j < 16; ++j)
            pe += wout_s[etg2][el2 + 16 * j] * h_cur[0][myb][el2 + 16 * j];
        pe += __shfl_xor(pe, 1); pe += __shfl_xor(pe, 2);
        pe += __shfl_xor(pe, 4); pe += __shfl_xor(pe, 8);
        if (el2 == 0)
            emp[(((size_t)(dir * BATCH) + gbatch) * SEQ + sp) * NT + etg2] = pe;
    }
}

// ---------------- K3: Viterbi decode per batch ----------------
__global__ __launch_bounds__(64) void k_viterbi(
    const float* __restrict__ emp, const float* __restrict__ b_out,
    const float* __restrict__ start_t, const float* __restrict__ end_t,
    const float* __restrict__ trans, const void* __restrict__ maskp,
    const int* __restrict__ mask_is_bool, int* __restrict__ out) {
    __shared__ float sh_em[SEQ][NT];
    __shared__ float sh_score[NT];
    __shared__ float sh_trans[NT * NT];
    __shared__ unsigned char sh_mask[SEQ];
    __shared__ unsigned char sh_hist[SEQ - 1][NT];
    __shared__ unsigned char sh_tags[SEQ];
    int b = blockIdx.x;
    int t = threadIdx.x;
    int isb = *mask_is_bool;
    for (int idx = t; idx < SEQ * NT; idx += 64) {
        int s = idx / NT, tg = idx % NT;
        sh_em[s][tg] = emp[((size_t)b * SEQ + s) * NT + tg]
                     + emp[(((size_t)BATCH + b) * SEQ + s) * NT + tg]
                     + b_out[tg];
    }
    if (isb) {
        const unsigned char* m8 = (const unsigned char*)maskp;
        for (int idx = t; idx < SEQ; idx += 64) sh_mask[idx] = m8[b * SEQ + idx];
    } else {
        const int* m32 = (const int*)maskp;
        for (int idx = t; idx < SEQ; idx += 64) sh_mask[idx] = (unsigned char)(m32[b * SEQ + idx] != 0);
    }
    for (int idx = t; idx < NT * NT; idx += 64) sh_trans[idx] = trans[idx];
    __syncthreads();
    float sc = 0.f;
    if (t < NT) { sc = start_t[t] + sh_em[0][t]; sh_score[t] = sc; }
    __syncthreads();
    for (int s = 1; s < SEQ; ++s) {
        if (t < NT) {
            float m = -3.4e38f; int bp = 0;
            #pragma unroll
            for (int i = 0; i < NT; ++i) {
                float v = sh_score[i] + sh_trans[i * NT + t];
                if (v > m) { m = v; bp = i; }
            }
            sh_hist[s - 1][t] = (unsigned char)bp;
            float best = m + sh_em[s][t];
            if (sh_mask[s]) sc = best;
        }
        __syncthreads();
        if (t < NT) sh_score[t] = sc;
        __syncthreads();
    }
    if (t == 0) {
        float bb = -3.4e38f; int tag = 0;
        for (int j = 0; j < NT; ++j) {
            float v = sh_score[j] + end_t[j];
            if (v > bb) { bb = v; tag = j; }
        }
        for (int pos = SEQ - 1; pos >= 1; --pos) {
            sh_tags[pos] = (unsigned char)tag;
            if (sh_mask[pos]) tag = sh_hist[pos - 1][tag];
        }
        sh_tags[0] = (unsigned char)tag;
    }
    __syncthreads();
    for (int idx = t; idx < SEQ; idx += 64) {
        out[b * SEQ + idx] = sh_mask[idx] ? (int)sh_tags[idx] : 0;
    }
}

extern "C" void kernel_launch(void* const* d_in, const int* in_sizes, int n_in,
                              void* d_out, int out_size, void* d_ws, size_t ws_size,
                              hipStream_t stream) {
    const int*   ids  = (const int*)d_in[0];
    const void*  mask = d_in[1];
    const float* emb  = (const float*)d_in[2];
    const float* Wihf = (const float*)d_in[3];
    const float* Whhf = (const float*)d_in[4];
    const float* bfv  = (const float*)d_in[5];
    const float* Wihb = (const float*)d_in[6];
    const float* Whhb = (const float*)d_in[7];
    const float* bbv  = (const float*)d_in[8];
    const float* Wout = (const float*)d_in[9];
    const float* bout = (const float*)d_in[10];
    const float* st   = (const float*)d_in[11];
    const float* en   = (const float*)d_in[12];
    const float* tr   = (const float*)d_in[13];
    int* out = (int*)d_out;

    char* ws = (char*)d_ws;
    float* table = (float*)ws;                                       // 245,760,000 B
    float* emp   = (float*)(ws + 245760000);                         //   4,718,592 B
    float* hx    = (float*)(ws + 245760000 + 4718592);               //     524,288 B
    int*   tags  = (int*)(ws + 245760000 + 4718592 + 524288);        //       2,048 B
    int*   flag  = (int*)(ws + 245760000 + 4718592 + 524288 + 2048); //           4 B

    k_detect<<<1, 128, 0, stream>>>((const unsigned char*)mask, flag);
    dim3 g1(32, 469);
    k_table_gemm<<<g1, 256, 0, stream>>>(emb, Wihf, Wihb, bfv, bbv, table);
    k_lstm_cl<<<256, 1024, 131072, stream>>>(ids, Whhf, Whhb, table, Wout, emp, hx, tags);
    k_viterbi<<<128, 64, 0, stream>>>(emp, bout, st, en, tr, mask, flag, out);
}

// Round 14
// 4038.758 us; speedup vs baseline: 1.3313x; 1.3313x over previous
//
#include <hip/hip_runtime.h>
#include <hip/hip_bf16.h>

#define SEQ   512
#define BATCH 128
#define VOCAB 30000
#define EDIM  256
#define HDIM  256
#define NT    9

// ---------------- K0b: detect mask storage dtype ----------------
__global__ void k_detect(const unsigned char* __restrict__ m, int* __restrict__ flag) {
    __shared__ int ok_sh;
    if (threadIdx.x == 0) ok_sh = 1;
    __syncthreads();
    int b = threadIdx.x;  // 128 threads, one row each
    const uint4* row = (const uint4*)(m + b * SEQ);
    int ok = 1, prev = 1;
    for (int i = 0; i < SEQ / 16; ++i) {
        uint4 v = row[i];
        unsigned w[4] = {v.x, v.y, v.z, v.w};
        #pragma unroll
        for (int wi = 0; wi < 4; ++wi) {
            #pragma unroll
            for (int j = 0; j < 4; ++j) {
                int byte = (w[wi] >> (8 * j)) & 255;
                if (byte > 1 || byte > prev) ok = 0;
                prev = byte;
            }
        }
    }
    if (!ok) atomicAnd(&ok_sh, 0);
    __syncthreads();
    if (threadIdx.x == 0) *flag = ok_sh;
}

// ---------------- K1: table[v][n] = embed[v] . Wcat[n] + bias[n] ----------------
__global__ __launch_bounds__(256) void k_table_gemm(
    const float* __restrict__ emb, const float* __restrict__ Wf,
    const float* __restrict__ Wb, const float* __restrict__ bf,
    const float* __restrict__ bb, float* __restrict__ table) {
    __shared__ __align__(16) float As[64][68];  // [k][m]
    __shared__ __align__(16) float Bs[64][68];  // [k][n]
    int t  = threadIdx.x;
    int tx = t & 15, ty = t >> 4;
    int n0 = blockIdx.x * 64;
    int v0 = blockIdx.y * 64;
    float acc[4][4] = {};
    for (int kc = 0; kc < 4; ++kc) {
        #pragma unroll
        for (int rr = 0; rr < 4; ++rr) {
            int slot = t + rr * 256;
            int m = slot >> 4, kq = slot & 15;
            int v = v0 + m;
            float4 a = (v < VOCAB)
                ? *(const float4*)&emb[v * EDIM + kc * 64 + kq * 4]
                : make_float4(0.f, 0.f, 0.f, 0.f);
            As[kq * 4 + 0][m] = a.x; As[kq * 4 + 1][m] = a.y;
            As[kq * 4 + 2][m] = a.z; As[kq * 4 + 3][m] = a.w;
            int n = n0 + m;
            const float* Wrow = (n < 1024) ? &Wf[n * 256] : &Wb[(n - 1024) * 256];
            float4 bvec = *(const float4*)&Wrow[kc * 64 + kq * 4];
            Bs[kq * 4 + 0][m] = bvec.x; Bs[kq * 4 + 1][m] = bvec.y;
            Bs[kq * 4 + 2][m] = bvec.z; Bs[kq * 4 + 3][m] = bvec.w;
        }
        __syncthreads();
        #pragma unroll
        for (int k = 0; k < 64; ++k) {
            float4 a = *(const float4*)&As[k][ty * 4];
            float4 b = *(const float4*)&Bs[k][tx * 4];
            acc[0][0] += a.x * b.x; acc[0][1] += a.x * b.y; acc[0][2] += a.x * b.z; acc[0][3] += a.x * b.w;
            acc[1][0] += a.y * b.x; acc[1][1] += a.y * b.y; acc[1][2] += a.y * b.z; acc[1][3] += a.y * b.w;
            acc[2][0] += a.z * b.x; acc[2][1] += a.z * b.y; acc[2][2] += a.z * b.z; acc[2][3] += a.z * b.w;
            acc[3][0] += a.w * b.x; acc[3][1] += a.w * b.y; acc[3][2] += a.w * b.z; acc[3][3] += a.w * b.w;
        }
        __syncthreads();
    }
    int n = n0 + tx * 4;
    const float* bi = (n < 1024) ? &bf[n] : &bb[n - 1024];
    float4 bias = *(const float4*)bi;
    #pragma unroll
    for (int i = 0; i < 4; ++i) {
        int v = v0 + ty * 4 + i;
        if (v < VOCAB) {
            float4 o;
            o.x = acc[i][0] + bias.x; o.y = acc[i][1] + bias.y;
            o.z = acc[i][2] + bias.z; o.w = acc[i][3] + bias.w;
            *(float4*)&table[(size_t)v * 2048 + n] = o;
        }
    }
}

// ---------------- K2: clustered LSTM, half-reg W, minimal-DS dot -------------
// 256 blocks x 512 threads (8 waves). cluster = bid>>3, myb = bid&7.
// Dot map (R=4, B=8, K=16 floats per thread): g = t>>4 owns rows 4g..4g+3;
// kc = t&15 owns k4 in {kc, kc+16, kc+32, kc+48}. Rows 4g,4g+1 weights live in
// 8 float4 REGISTERS (loaded once from global); rows 4g+2,4g+3 read from LDS
// (contiguous 256B/16-lane phases, conflict-free). h read linear, 2-way free.
// Reduction: 4-stage thinning butterfly over 16 kc-lanes (strides 1,2,4,8);
// lane kc ends with a[0] = gates m0, a[1] = m0+1, m0 = ((kc&1)<<4)|((kc&2)<<2)
// |(kc&4)|((kc&8)>>2)  (r = m0>>3, b = m0&7); stores to sh_g[8][132] (pad 132
// => banks 4b+4g+r bijective, conflict-free).
// Exchange protocol identical to r9-r12 (proven): relaxed agent atomics -> L3,
// per-wave vmcnt(0), LDS ctr (4 nonlin waves) -> t0 publishes monotonic tag,
// 2-slot ring; copy duty: wave wv polls+copies peer wv (skip myb). 2 barriers.
__global__ __attribute__((amdgpu_flat_work_group_size(512, 512), amdgpu_waves_per_eu(2, 2)))
void k_lstm_cl(
    const int* __restrict__ ids, const float* __restrict__ Whhf,
    const float* __restrict__ Whhb, const float* __restrict__ table,
    const float* __restrict__ Wout, float* __restrict__ emp,
    float* hx, int* tagbuf) {
    extern __shared__ float sh_w[];            // [128][256] linear = 128 KB
    __shared__ float h_cur[8][256];            // 8 KB linear
    __shared__ float h_em[256];                // 1 KB stash (batch myb, h_{it-1})
    __shared__ float sh_g[8][132];             // gates [batch][gate*32+dim], pad
    __shared__ float wout_s[NT][257];
    __shared__ int   sh_ctr;

    const int t   = threadIdx.x;
    const int bid = blockIdx.x;
    const int cluster = bid >> 3;
    const int myb = bid & 7;
    const int dir = cluster & 1;
    const int oct = cluster >> 1;
    const int gbatch = oct * 8 + myb;

    const int lane = t & 63;
    const int wv   = t >> 6;                   // 0..7
    const int g    = t >> 4;                   // row-group 0..31
    const int kc   = t & 15;                   // k lane 0..15

    const int nb = t >> 5, nd = t & 31;        // nonlin map (t<256)
    const int em = t - 256;                    // emission map (256<=t<400)
    const int etg = em >> 4, el = em & 15;

    const float* Whh = dir ? Whhb : Whhf;

    if (t == 0) sh_ctr = 0;
    for (int idx = t; idx < NT * 256; idx += 512)
        wout_s[idx >> 8][idx & 255] = Wout[(idx >> 8) * 512 + dir * 256 + (idx & 255)];
    // stage full W-slice into LDS (2 passes, coalesced)
    #pragma unroll
    for (int pass = 0; pass < 2; ++pass) {
        int tt = t + pass * 512;
        int lr = tt >> 3, seg = tt & 7;
        int grow = (lr >> 5) * 256 + myb * 32 + (lr & 31);
        const float4* src = (const float4*)(Whh + (size_t)grow * 256) + seg * 8;
        float4* dst = (float4*)(sh_w + lr * 256) + seg * 8;
        #pragma unroll
        for (int i = 0; i < 8; ++i) dst[i] = src[i];
    }
    for (int idx = t; idx < 2048; idx += 512)
        h_cur[idx >> 8][idx & 255] = 0.f;
    float c_state = 0.f;

    // register-resident W rows 4g, 4g+1 (loaded once, coalesced per 16 lanes)
    float4 w0_0, w0_1, w0_2, w0_3, w1_0, w1_1, w1_2, w1_3;
    {
        int lr0 = 4 * g, lr1 = 4 * g + 1;
        int gr0 = (lr0 >> 5) * 256 + myb * 32 + (lr0 & 31);
        int gr1 = (lr1 >> 5) * 256 + myb * 32 + (lr1 & 31);
        const float4* wp0 = (const float4*)(Whh + (size_t)gr0 * 256);
        const float4* wp1 = (const float4*)(Whh + (size_t)gr1 * 256);
        w0_0 = wp0[kc];      w0_1 = wp0[kc + 16];
        w0_2 = wp0[kc + 32]; w0_3 = wp0[kc + 48];
        w1_0 = wp1[kc];      w1_1 = wp1[kc + 16];
        w1_2 = wp1[kc + 32]; w1_3 = wp1[kc + 48];
    }
    const float* w2p = sh_w + (4 * g + 2) * 256;
    const float* w3p = sh_w + (4 * g + 3) * 256;
    __syncthreads();

    // xg prefetch for it=0 (nonlin threads hold i,f,g,o in regs)
    float xi = 0.f, xf = 0.f, xq = 0.f, xo = 0.f;
    if (t < 256) {
        int s0 = dir ? SEQ - 1 : 0;
        int id = ids[(oct * 8 + nb) * SEQ + s0];
        const float* tb = table + (size_t)id * 2048 + dir * 1024;
        int base = myb * 32 + nd;
        xi = tb[base]; xf = tb[256 + base]; xq = tb[512 + base]; xo = tb[768 + base];
    }

    #pragma unroll 1
    for (int it = 0; it < SEQ; ++it) {
        // stash h_em (emission source) + dot
        if (t < 256) h_em[t] = h_cur[myb][t];

        float a[32];
        #pragma unroll
        for (int m = 0; m < 32; ++m) a[m] = 0.f;

        #define DOTJ(J, W0, W1) { \
            const int off = 4 * (kc + 16 * (J)); \
            float4 w2 = *(const float4*)(w2p + off); \
            float4 w3 = *(const float4*)(w3p + off); \
            _Pragma("unroll") \
            for (int b = 0; b < 8; ++b) { \
                float4 hv = *(const float4*)(&h_cur[b][0] + off); \
                a[b]      += W0.x*hv.x + W0.y*hv.y + W0.z*hv.z + W0.w*hv.w; \
                a[8 + b]  += W1.x*hv.x + W1.y*hv.y + W1.z*hv.z + W1.w*hv.w; \
                a[16 + b] += w2.x*hv.x + w2.y*hv.y + w2.z*hv.z + w2.w*hv.w; \
                a[24 + b] += w3.x*hv.x + w3.y*hv.y + w3.z*hv.z + w3.w*hv.w; } }
        DOTJ(0, w0_0, w1_0)
        DOTJ(1, w0_1, w1_1)
        DOTJ(2, w0_2, w1_2)
        DOTJ(3, w0_3, w1_3)
        #undef DOTJ

        // 4-stage thinning butterfly over the 16 kc-lanes (strides 1,2,4,8)
        #pragma unroll
        for (int m = 0; m < 16; ++m) {
            int bit = kc & 1;
            float sent = bit ? a[m] : a[m + 16];
            float recv = __shfl_xor(sent, 1);
            a[m] = (bit ? a[m + 16] : a[m]) + recv;
        }
        #pragma unroll
        for (int m = 0; m < 8; ++m) {
            int bit = kc & 2;
            float sent = bit ? a[m] : a[m + 8];
            float recv = __shfl_xor(sent, 2);
            a[m] = (bit ? a[m + 8] : a[m]) + recv;
        }
        #pragma unroll
        for (int m = 0; m < 4; ++m) {
            int bit = kc & 4;
            float sent = bit ? a[m] : a[m + 4];
            float recv = __shfl_xor(sent, 4);
            a[m] = (bit ? a[m + 4] : a[m]) + recv;
        }
        #pragma unroll
        for (int m = 0; m < 2; ++m) {
            int bit = kc & 8;
            float sent = bit ? a[m] : a[m + 2];
            float recv = __shfl_xor(sent, 8);
            a[m] = (bit ? a[m + 2] : a[m]) + recv;
        }
        {
            // lane kc holds gates m0 (a[0]) and m0+1 (a[1]); m0 = r*8+b, b even
            int m0 = ((kc & 1) << 4) | ((kc & 2) << 2) | (kc & 4) | ((kc & 8) >> 2);
            int r = m0 >> 3, b = m0 & 7;
            sh_g[b][4 * g + r] = a[0];
            sh_g[b + 1][4 * g + r] = a[1];
        }
        __syncthreads();   // BARRIER A: gates ready, h_cur reads done, h_em ready

        const int p = it & 1;
        float* hxp = hx + (size_t)p * 65536 + (size_t)cluster * 2048;
        int* tags = tagbuf + p * 256 + cluster * 8;

        if (t < 256) {
            // nonlin + publish (waves 0-3)
            float iv = sh_g[nb][nd]      + xi;
            float fv = sh_g[nb][32 + nd] + xf;
            float gv = sh_g[nb][64 + nd] + xq;
            float ov = sh_g[nb][96 + nd] + xo;
            float si = 1.f / (1.f + expf(-iv));
            float sf = 1.f / (1.f + expf(-fv));
            float so = 1.f / (1.f + expf(-ov));
            float tg = tanhf(gv);
            c_state = sf * c_state + si * tg;
            float hh = so * tanhf(c_state);
            int dl = myb * 32 + nd;
            h_cur[nb][dl] = hh;
            __hip_atomic_store(&hxp[nb * 256 + dl], hh,
                               __ATOMIC_RELAXED, __HIP_MEMORY_SCOPE_AGENT);
            asm volatile("s_waitcnt vmcnt(0)" ::: "memory");
            if (lane == 0) atomicAdd(&sh_ctr, 1);
            if (t == 0) {
                while (__hip_atomic_load(&sh_ctr, __ATOMIC_RELAXED,
                                         __HIP_MEMORY_SCOPE_WORKGROUP) < 4 * (it + 1)) {}
                __hip_atomic_store(&tags[myb], it,
                                   __ATOMIC_RELAXED, __HIP_MEMORY_SCOPE_AGENT);
            }
            // xg prefetch for it+1 (completes during next dot)
            if (it < SEQ - 1) {
                int sn = dir ? (SEQ - 2 - it) : (it + 1);
                int id = ids[(oct * 8 + nb) * SEQ + sn];
                const float* tb = table + (size_t)id * 2048 + dir * 1024;
                int base = myb * 32 + nd;
                xi = tb[base]; xf = tb[256 + base]; xq = tb[512 + base]; xo = tb[768 + base];
            }
        } else if (em < 144) {
            // emission for h_{it-1} from linear stash (waves 4-6 partial)
            if (it > 0) {
                int sp = dir ? (SEQ - it) : (it - 1);
                float pe = 0.f;
                #pragma unroll
                for (int j = 0; j < 16; ++j)
                    pe += wout_s[etg][el + 16 * j] * h_em[el + 16 * j];
                pe += __shfl_xor(pe, 1); pe += __shfl_xor(pe, 2);
                pe += __shfl_xor(pe, 4); pe += __shfl_xor(pe, 8);
                if (el == 0)
                    emp[(((size_t)(dir * BATCH) + gbatch) * SEQ + sp) * NT + etg] = pe;
            }
        }

        // copy duty: wave wv polls + copies peer wv (skip own chunk)
        if (wv != myb) {
            while (__hip_atomic_load(&tags[wv], __ATOMIC_RELAXED,
                                     __HIP_MEMORY_SCOPE_AGENT) != it)
                __builtin_amdgcn_s_sleep(1);
            #pragma unroll
            for (int rep = 0; rep < 4; ++rep) {
                int idx = rep * 64 + lane;
                int nb2 = idx >> 5, nd2 = idx & 31;
                float vv = __hip_atomic_load(&hxp[nb2 * 256 + wv * 32 + nd2],
                                             __ATOMIC_RELAXED, __HIP_MEMORY_SCOPE_AGENT);
                h_cur[nb2][wv * 32 + nd2] = vv;
            }
        }
        __syncthreads();   // BARRIER B: h_cur = full h_it
    }

    // final emission for h_{511}
    if (t < 256) h_em[t] = h_cur[myb][t];
    __syncthreads();
    if (t < 144) {
        int etg2 = t >> 4, el2 = t & 15;
        int sp = dir ? 0 : (SEQ - 1);
        float pe = 0.f;
        #pragma unroll
        for (int j = 0; j < 16; ++j)
            pe += wout_s[etg2][el2 + 16 * j] * h_em[el2 + 16 * j];
        pe += __shfl_xor(pe, 1); pe += __shfl_xor(pe, 2);
        pe += __shfl_xor(pe, 4); pe += __shfl_xor(pe, 8);
        if (el2 == 0)
            emp[(((size_t)(dir * BATCH) + gbatch) * SEQ + sp) * NT + etg2] = pe;
    }
}

// ---------------- K3: Viterbi decode per batch ----------------
__global__ __launch_bounds__(64) void k_viterbi(
    const float* __restrict__ emp, const float* __restrict__ b_out,
    const float* __restrict__ start_t, const float* __restrict__ end_t,
    const float* __restrict__ trans, const void* __restrict__ maskp,
    const int* __restrict__ mask_is_bool, int* __restrict__ out) {
    __shared__ float sh_em[SEQ][NT];
    __shared__ float sh_score[NT];
    __shared__ float sh_trans[NT * NT];
    __shared__ unsigned char sh_mask[SEQ];
    __shared__ unsigned char sh_hist[SEQ - 1][NT];
    __shared__ unsigned char sh_tags[SEQ];
    int b = blockIdx.x;
    int t = threadIdx.x;
    int isb = *mask_is_bool;
    for (int idx = t; idx < SEQ * NT; idx += 64) {
        int s = idx / NT, tg = idx % NT;
        sh_em[s][tg] = emp[((size_t)b * SEQ + s) * NT + tg]
                     + emp[(((size_t)BATCH + b) * SEQ + s) * NT + tg]
                     + b_out[tg];
    }
    if (isb) {
        const unsigned char* m8 = (const unsigned char*)maskp;
        for (int idx = t; idx < SEQ; idx += 64) sh_mask[idx] = m8[b * SEQ + idx];
    } else {
        const int* m32 = (const int*)maskp;
        for (int idx = t; idx < SEQ; idx += 64) sh_mask[idx] = (unsigned char)(m32[b * SEQ + idx] != 0);
    }
    for (int idx = t; idx < NT * NT; idx += 64) sh_trans[idx] = trans[idx];
    __syncthreads();
    float sc = 0.f;
    if (t < NT) { sc = start_t[t] + sh_em[0][t]; sh_score[t] = sc; }
    __syncthreads();
    for (int s = 1; s < SEQ; ++s) {
        if (t < NT) {
            float m = -3.4e38f; int bp = 0;
            #pragma unroll
            for (int i = 0; i < NT; ++i) {
                float v = sh_score[i] + sh_trans[i * NT + t];
                if (v > m) { m = v; bp = i; }
            }
            sh_hist[s - 1][t] = (unsigned char)bp;
            float best = m + sh_em[s][t];
            if (sh_mask[s]) sc = best;
        }
        __syncthreads();
        if (t < NT) sh_score[t] = sc;
        __syncthreads();
    }
    if (t == 0) {
        float bb = -3.4e38f; int tag = 0;
        for (int j = 0; j < NT; ++j) {
            float v = sh_score[j] + end_t[j];
            if (v > bb) { bb = v; tag = j; }
        }
        for (int pos = SEQ - 1; pos >= 1; --pos) {
            sh_tags[pos] = (unsigned char)tag;
            if (sh_mask[pos]) tag = sh_hist[pos - 1][tag];
        }
        sh_tags[0] = (unsigned char)tag;
    }
    __syncthreads();
    for (int idx = t; idx < SEQ; idx += 64) {
        out[b * SEQ + idx] = sh_mask[idx] ? (int)sh_tags[idx] : 0;
    }
}

extern "C" void kernel_launch(void* const* d_in, const int* in_sizes, int n_in,
                              void* d_out, int out_size, void* d_ws, size_t ws_size,
                              hipStream_t stream) {
    const int*   ids  = (const int*)d_in[0];
    const void*  mask = d_in[1];
    const float* emb  = (const float*)d_in[2];
    const float* Wihf = (const float*)d_in[3];
    const float* Whhf = (const float*)d_in[4];
    const float* bfv  = (const float*)d_in[5];
    const float* Wihb = (const float*)d_in[6];
    const float* Whhb = (const float*)d_in[7];
    const float* bbv  = (const float*)d_in[8];
    const float* Wout = (const float*)d_in[9];
    const float* bout = (const float*)d_in[10];
    const float* st   = (const float*)d_in[11];
    const float* en   = (const float*)d_in[12];
    const float* tr   = (const float*)d_in[13];
    int* out = (int*)d_out;

    char* ws = (char*)d_ws;
    float* table = (float*)ws;                                       // 245,760,000 B
    float* emp   = (float*)(ws + 245760000);                         //   4,718,592 B
    float* hx    = (float*)(ws + 245760000 + 4718592);               //     524,288 B
    int*   tags  = (int*)(ws + 245760000 + 4718592 + 524288);        //       2,048 B
    int*   flag  = (int*)(ws + 245760000 + 4718592 + 524288 + 2048); //           4 B

    k_detect<<<1, 128, 0, stream>>>((const unsigned char*)mask, flag);
    dim3 g1(32, 469);
    k_table_gemm<<<g1, 256, 0, stream>>>(emb, Wihf, Wihb, bfv, bbv, table);
    k_lstm_cl<<<256, 512, 131072, stream>>>(ids, Whhf, Whhb, table, Wout, emp, hx, tags);
    k_viterbi<<<128, 64, 0, stream>>>(emp, bout, st, en, tr, mask, flag, out);
}

// Round 15
// 3861.169 us; speedup vs baseline: 1.3926x; 1.0460x over previous
//
#include <hip/hip_runtime.h>
#include <hip/hip_bf16.h>

#define SEQ   512
#define BATCH 128
#define VOCAB 30000
#define EDIM  256
#define HDIM  256
#define NT    9

// ---------------- K0b: detect mask storage dtype ----------------
__global__ void k_detect(const unsigned char* __restrict__ m, int* __restrict__ flag) {
    __shared__ int ok_sh;
    if (threadIdx.x == 0) ok_sh = 1;
    __syncthreads();
    int b = threadIdx.x;  // 128 threads, one row each
    const uint4* row = (const uint4*)(m + b * SEQ);
    int ok = 1, prev = 1;
    for (int i = 0; i < SEQ / 16; ++i) {
        uint4 v = row[i];
        unsigned w[4] = {v.x, v.y, v.z, v.w};
        #pragma unroll
        for (int wi = 0; wi < 4; ++wi) {
            #pragma unroll
            for (int j = 0; j < 4; ++j) {
                int byte = (w[wi] >> (8 * j)) & 255;
                if (byte > 1 || byte > prev) ok = 0;
                prev = byte;
            }
        }
    }
    if (!ok) atomicAnd(&ok_sh, 0);
    __syncthreads();
    if (threadIdx.x == 0) *flag = ok_sh;
}

// ---------------- K1: table[v][n] = embed[v] . Wcat[n] + bias[n] ----------------
__global__ __launch_bounds__(256) void k_table_gemm(
    const float* __restrict__ emb, const float* __restrict__ Wf,
    const float* __restrict__ Wb, const float* __restrict__ bf,
    const float* __restrict__ bb, float* __restrict__ table) {
    __shared__ __align__(16) float As[64][68];  // [k][m]
    __shared__ __align__(16) float Bs[64][68];  // [k][n]
    int t  = threadIdx.x;
    int tx = t & 15, ty = t >> 4;
    int n0 = blockIdx.x * 64;
    int v0 = blockIdx.y * 64;
    float acc[4][4] = {};
    for (int kc = 0; kc < 4; ++kc) {
        #pragma unroll
        for (int rr = 0; rr < 4; ++rr) {
            int slot = t + rr * 256;
            int m = slot >> 4, kq = slot & 15;
            int v = v0 + m;
            float4 a = (v < VOCAB)
                ? *(const float4*)&emb[v * EDIM + kc * 64 + kq * 4]
                : make_float4(0.f, 0.f, 0.f, 0.f);
            As[kq * 4 + 0][m] = a.x; As[kq * 4 + 1][m] = a.y;
            As[kq * 4 + 2][m] = a.z; As[kq * 4 + 3][m] = a.w;
            int n = n0 + m;
            const float* Wrow = (n < 1024) ? &Wf[n * 256] : &Wb[(n - 1024) * 256];
            float4 bvec = *(const float4*)&Wrow[kc * 64 + kq * 4];
            Bs[kq * 4 + 0][m] = bvec.x; Bs[kq * 4 + 1][m] = bvec.y;
            Bs[kq * 4 + 2][m] = bvec.z; Bs[kq * 4 + 3][m] = bvec.w;
        }
        __syncthreads();
        #pragma unroll
        for (int k = 0; k < 64; ++k) {
            float4 a = *(const float4*)&As[k][ty * 4];
            float4 b = *(const float4*)&Bs[k][tx * 4];
            acc[0][0] += a.x * b.x; acc[0][1] += a.x * b.y; acc[0][2] += a.x * b.z; acc[0][3] += a.x * b.w;
            acc[1][0] += a.y * b.x; acc[1][1] += a.y * b.y; acc[1][2] += a.y * b.z; acc[1][3] += a.y * b.w;
            acc[2][0] += a.z * b.x; acc[2][1] += a.z * b.y; acc[2][2] += a.z * b.z; acc[2][3] += a.z * b.w;
            acc[3][0] += a.w * b.x; acc[3][1] += a.w * b.y; acc[3][2] += a.w * b.z; acc[3][3] += a.w * b.w;
        }
        __syncthreads();
    }
    int n = n0 + tx * 4;
    const float* bi = (n < 1024) ? &bf[n] : &bb[n - 1024];
    float4 bias = *(const float4*)bi;
    #pragma unroll
    for (int i = 0; i < 4; ++i) {
        int v = v0 + ty * 4 + i;
        if (v < VOCAB) {
            float4 o;
            o.x = acc[i][0] + bias.x; o.y = acc[i][1] + bias.y;
            o.z = acc[i][2] + bias.z; o.w = acc[i][3] + bias.w;
            *(float4*)&table[(size_t)v * 2048 + n] = o;
        }
    }
}

// ---------------- K2: clustered LSTM, FULL-REG W, DPP butterfly --------------
// 256 blocks x 512 threads (8 waves). cluster = bid>>3, myb = bid&7.
// Dot map (R=4, B=8, K=16 floats per thread): g = t>>4 owns rows 4g..4g+3;
// kc = t&15 owns k4 in {kc, kc+16, kc+32, kc+48}. ALL 4 rows' weights live in
// 16 float4 REGISTERS (64 VGPRs, loaded once; r14 proved 2-row version does
// not remat/spill at VGPR=88; predicted ~120 <= observed 128 cap).
// No sh_w at all -> LDS ~23 KB static, no W staging, no W LDS reads.
// Reduction: 4-stage thinning butterfly; strides 1,2,8 via DPP (VALU pipe:
// quad_perm 0xB1 / 0x4E, row_ror:8 0x128 -- exact __shfl_xor semantics within
// 16-lane rows), stride 4 via __shfl_xor (DS). Lane kc ends with a[0] = gate
// tile m0, a[1] = m0+1, m0 = ((kc&1)<<4)|((kc&2)<<2)|(kc&4)|((kc&8)>>2)
// (r14-verified); stores to sh_g[8][132] (pad -> conflict-free).
// Exchange protocol identical to r9-r14 (proven): relaxed agent atomics -> L3,
// per-wave vmcnt(0), LDS ctr (4 nonlin waves) -> t0 publishes monotonic tag,
// 2-slot ring; copy duty: wave wv polls+copies peer wv (skip myb). 2 barriers.
#define DPPXOR(dst, src, CTRL) { \
    int _i = __float_as_int(src); \
    int _r = __builtin_amdgcn_update_dpp(_i, _i, (CTRL), 0xF, 0xF, false); \
    dst = __int_as_float(_r); }

__global__ __attribute__((amdgpu_flat_work_group_size(512, 512), amdgpu_waves_per_eu(2, 2)))
void k_lstm_cl(
    const int* __restrict__ ids, const float* __restrict__ Whhf,
    const float* __restrict__ Whhb, const float* __restrict__ table,
    const float* __restrict__ Wout, float* __restrict__ emp,
    float* hx, int* tagbuf) {
    __shared__ float h_cur[8][256];            // 8 KB linear
    __shared__ float h_em[256];                // 1 KB stash (batch myb, h_{it-1})
    __shared__ float sh_g[8][132];             // gates [batch][gate*32+dim], pad
    __shared__ float wout_s[NT][257];
    __shared__ int   sh_ctr;

    const int t   = threadIdx.x;
    const int bid = blockIdx.x;
    const int cluster = bid >> 3;
    const int myb = bid & 7;
    const int dir = cluster & 1;
    const int oct = cluster >> 1;
    const int gbatch = oct * 8 + myb;

    const int lane = t & 63;
    const int wv   = t >> 6;                   // 0..7
    const int g    = t >> 4;                   // row-group 0..31
    const int kc   = t & 15;                   // k lane 0..15

    const int nb = t >> 5, nd = t & 31;        // nonlin map (t<256)
    const int em = t - 256;                    // emission map (256<=t<400)
    const int etg = em >> 4, el = em & 15;

    const float* Whh = dir ? Whhb : Whhf;

    if (t == 0) sh_ctr = 0;
    for (int idx = t; idx < NT * 256; idx += 512)
        wout_s[idx >> 8][idx & 255] = Wout[(idx >> 8) * 512 + dir * 256 + (idx & 255)];
    for (int idx = t; idx < 2048; idx += 512)
        h_cur[idx >> 8][idx & 255] = 0.f;
    float c_state = 0.f;

    // FULL register-resident W: rows 4g..4g+3, 4 float4 chunks each (64 VGPR)
    float4 w0_0, w0_1, w0_2, w0_3, w1_0, w1_1, w1_2, w1_3;
    float4 w2_0, w2_1, w2_2, w2_3, w3_0, w3_1, w3_2, w3_3;
    {
        int lr0 = 4 * g, lr1 = 4 * g + 1, lr2 = 4 * g + 2, lr3 = 4 * g + 3;
        int gr0 = (lr0 >> 5) * 256 + myb * 32 + (lr0 & 31);
        int gr1 = (lr1 >> 5) * 256 + myb * 32 + (lr1 & 31);
        int gr2 = (lr2 >> 5) * 256 + myb * 32 + (lr2 & 31);
        int gr3 = (lr3 >> 5) * 256 + myb * 32 + (lr3 & 31);
        const float4* wp0 = (const float4*)(Whh + (size_t)gr0 * 256);
        const float4* wp1 = (const float4*)(Whh + (size_t)gr1 * 256);
        const float4* wp2 = (const float4*)(Whh + (size_t)gr2 * 256);
        const float4* wp3 = (const float4*)(Whh + (size_t)gr3 * 256);
        w0_0 = wp0[kc]; w0_1 = wp0[kc + 16]; w0_2 = wp0[kc + 32]; w0_3 = wp0[kc + 48];
        w1_0 = wp1[kc]; w1_1 = wp1[kc + 16]; w1_2 = wp1[kc + 32]; w1_3 = wp1[kc + 48];
        w2_0 = wp2[kc]; w2_1 = wp2[kc + 16]; w2_2 = wp2[kc + 32]; w2_3 = wp2[kc + 48];
        w3_0 = wp3[kc]; w3_1 = wp3[kc + 16]; w3_2 = wp3[kc + 32]; w3_3 = wp3[kc + 48];
    }
    __syncthreads();

    // xg prefetch for it=0 (nonlin threads hold i,f,g,o in regs)
    float xi = 0.f, xf = 0.f, xq = 0.f, xo = 0.f;
    if (t < 256) {
        int s0 = dir ? SEQ - 1 : 0;
        int id = ids[(oct * 8 + nb) * SEQ + s0];
        const float* tb = table + (size_t)id * 2048 + dir * 1024;
        int base = myb * 32 + nd;
        xi = tb[base]; xf = tb[256 + base]; xq = tb[512 + base]; xo = tb[768 + base];
    }

    #pragma unroll 1
    for (int it = 0; it < SEQ; ++it) {
        // stash h_em (emission source) + dot
        if (t < 256) h_em[t] = h_cur[myb][t];

        float a[32];
        #pragma unroll
        for (int m = 0; m < 32; ++m) a[m] = 0.f;

        #define DOTJ(J, W0, W1, W2, W3) { \
            const int off = 4 * (kc + 16 * (J)); \
            _Pragma("unroll") \
            for (int b = 0; b < 8; ++b) { \
                float4 hv = *(const float4*)(&h_cur[b][0] + off); \
                a[b]      += W0.x*hv.x + W0.y*hv.y + W0.z*hv.z + W0.w*hv.w; \
                a[8 + b]  += W1.x*hv.x + W1.y*hv.y + W1.z*hv.z + W1.w*hv.w; \
                a[16 + b] += W2.x*hv.x + W2.y*hv.y + W2.z*hv.z + W2.w*hv.w; \
                a[24 + b] += W3.x*hv.x + W3.y*hv.y + W3.z*hv.z + W3.w*hv.w; } }
        DOTJ(0, w0_0, w1_0, w2_0, w3_0)
        DOTJ(1, w0_1, w1_1, w2_1, w3_1)
        DOTJ(2, w0_2, w1_2, w2_2, w3_2)
        DOTJ(3, w0_3, w1_3, w2_3, w3_3)
        #undef DOTJ

        // 4-stage thinning butterfly over 16 kc-lanes.
        // strides 1,2,8: DPP (VALU); stride 4: __shfl_xor (DS).
        #pragma unroll
        for (int m = 0; m < 16; ++m) {          // stride 1: quad_perm [1,0,3,2]
            int bit = kc & 1;
            float sent = bit ? a[m] : a[m + 16];
            float recv; DPPXOR(recv, sent, 0xB1)
            a[m] = (bit ? a[m + 16] : a[m]) + recv;
        }
        #pragma unroll
        for (int m = 0; m < 8; ++m) {           // stride 2: quad_perm [2,3,0,1]
            int bit = kc & 2;
            float sent = bit ? a[m] : a[m + 8];
            float recv; DPPXOR(recv, sent, 0x4E)
            a[m] = (bit ? a[m + 8] : a[m]) + recv;
        }
        #pragma unroll
        for (int m = 0; m < 4; ++m) {           // stride 4: ds shuffle
            int bit = kc & 4;
            float sent = bit ? a[m] : a[m + 4];
            float recv = __shfl_xor(sent, 4);
            a[m] = (bit ? a[m + 4] : a[m]) + recv;
        }
        #pragma unroll
        for (int m = 0; m < 2; ++m) {           // stride 8: row_ror:8
            int bit = kc & 8;
            float sent = bit ? a[m] : a[m + 2];
            float recv; DPPXOR(recv, sent, 0x128)
            a[m] = (bit ? a[m + 2] : a[m]) + recv;
        }
        {
            // lane kc holds gates m0 (a[0]) and m0+1 (a[1]); m0 = r*8+b, b even
            int m0 = ((kc & 1) << 4) | ((kc & 2) << 2) | (kc & 4) | ((kc & 8) >> 2);
            int r = m0 >> 3, b = m0 & 7;
            sh_g[b][4 * g + r] = a[0];
            sh_g[b + 1][4 * g + r] = a[1];
        }
        __syncthreads();   // BARRIER A: gates ready, h_cur reads done, h_em ready

        const int p = it & 1;
        float* hxp = hx + (size_t)p * 65536 + (size_t)cluster * 2048;
        int* tags = tagbuf + p * 256 + cluster * 8;

        if (t < 256) {
            // nonlin + publish (waves 0-3)
            float iv = sh_g[nb][nd]      + xi;
            float fv = sh_g[nb][32 + nd] + xf;
            float gv = sh_g[nb][64 + nd] + xq;
            float ov = sh_g[nb][96 + nd] + xo;
            float si = 1.f / (1.f + expf(-iv));
            float sf = 1.f / (1.f + expf(-fv));
            float so = 1.f / (1.f + expf(-ov));
            float tg = tanhf(gv);
            c_state = sf * c_state + si * tg;
            float hh = so * tanhf(c_state);
            int dl = myb * 32 + nd;
            h_cur[nb][dl] = hh;
            __hip_atomic_store(&hxp[nb * 256 + dl], hh,
                               __ATOMIC_RELAXED, __HIP_MEMORY_SCOPE_AGENT);
            asm volatile("s_waitcnt vmcnt(0)" ::: "memory");
            if (lane == 0) atomicAdd(&sh_ctr, 1);
            if (t == 0) {
                while (__hip_atomic_load(&sh_ctr, __ATOMIC_RELAXED,
                                         __HIP_MEMORY_SCOPE_WORKGROUP) < 4 * (it + 1)) {}
                __hip_atomic_store(&tags[myb], it,
                                   __ATOMIC_RELAXED, __HIP_MEMORY_SCOPE_AGENT);
            }
            // xg prefetch for it+1 (completes during next dot)
            if (it < SEQ - 1) {
                int sn = dir ? (SEQ - 2 - it) : (it + 1);
                int id = ids[(oct * 8 + nb) * SEQ + sn];
                const float* tb = table + (size_t)id * 2048 + dir * 1024;
                int base = myb * 32 + nd;
                xi = tb[base]; xf = tb[256 + base]; xq = tb[512 + base]; xo = tb[768 + base];
            }
        } else if (em < 144) {
            // emission for h_{it-1} from linear stash (waves 4-6 partial)
            if (it > 0) {
                int sp = dir ? (SEQ - it) : (it - 1);
                float pe = 0.f;
                #pragma unroll
                for (int j = 0; j < 16; ++j)
                    pe += wout_s[etg][el + 16 * j] * h_em[el + 16 * j];
                pe += __shfl_xor(pe, 1); pe += __shfl_xor(pe, 2);
                pe += __shfl_xor(pe, 4); pe += __shfl_xor(pe, 8);
                if (el == 0)
                    emp[(((size_t)(dir * BATCH) + gbatch) * SEQ + sp) * NT + etg] = pe;
            }
        }

        // copy duty: wave wv polls + copies peer wv (skip own chunk)
        if (wv != myb) {
            while (__hip_atomic_load(&tags[wv], __ATOMIC_RELAXED,
                                     __HIP_MEMORY_SCOPE_AGENT) != it)
                __builtin_amdgcn_s_sleep(1);
            #pragma unroll
            for (int rep = 0; rep < 4; ++rep) {
                int idx = rep * 64 + lane;
                int nb2 = idx >> 5, nd2 = idx & 31;
                float vv = __hip_atomic_load(&hxp[nb2 * 256 + wv * 32 + nd2],
                                             __ATOMIC_RELAXED, __HIP_MEMORY_SCOPE_AGENT);
                h_cur[nb2][wv * 32 + nd2] = vv;
            }
        }
        __syncthreads();   // BARRIER B: h_cur = full h_it
    }

    // final emission for h_{511}
    if (t < 256) h_em[t] = h_cur[myb][t];
    __syncthreads();
    if (t < 144) {
        int etg2 = t >> 4, el2 = t & 15;
        int sp = dir ? 0 : (SEQ - 1);
        float pe = 0.f;
        #pragma unroll
        for (int j = 0; j < 16; ++j)
            pe += wout_s[etg2][el2 + 16 * j] * h_em[el2 + 16 * j];
        pe += __shfl_xor(pe, 1); pe += __shfl_xor(pe, 2);
        pe += __shfl_xor(pe, 4); pe += __shfl_xor(pe, 8);
        if (el2 == 0)
            emp[(((size_t)(dir * BATCH) + gbatch) * SEQ + sp) * NT + etg2] = pe;
    }
}

// ---------------- K3: Viterbi decode per batch ----------------
__global__ __launch_bounds__(64) void k_viterbi(
    const float* __restrict__ emp, const float* __restrict__ b_out,
    const float* __restrict__ start_t, const float* __restrict__ end_t,
    const float* __restrict__ trans, const void* __restrict__ maskp,
    const int* __restrict__ mask_is_bool, int* __restrict__ out) {
    __shared__ float sh_em[SEQ][NT];
    __shared__ float sh_score[NT];
    __shared__ float sh_trans[NT * NT];
    __shared__ unsigned char sh_mask[SEQ];
    __shared__ unsigned char sh_hist[SEQ - 1][NT];
    __shared__ unsigned char sh_tags[SEQ];
    int b = blockIdx.x;
    int t = threadIdx.x;
    int isb = *mask_is_bool;
    for (int idx = t; idx < SEQ * NT; idx += 64) {
        int s = idx / NT, tg = idx % NT;
        sh_em[s][tg] = emp[((size_t)b * SEQ + s) * NT + tg]
                     + emp[(((size_t)BATCH + b) * SEQ + s) * NT + tg]
                     + b_out[tg];
    }
    if (isb) {
        const unsigned char* m8 = (const unsigned char*)maskp;
        for (int idx = t; idx < SEQ; idx += 64) sh_mask[idx] = m8[b * SEQ + idx];
    } else {
        const int* m32 = (const int*)maskp;
        for (int idx = t; idx < SEQ; idx += 64) sh_mask[idx] = (unsigned char)(m32[b * SEQ + idx] != 0);
    }
    for (int idx = t; idx < NT * NT; idx += 64) sh_trans[idx] = trans[idx];
    __syncthreads();
    float sc = 0.f;
    if (t < NT) { sc = start_t[t] + sh_em[0][t]; sh_score[t] = sc; }
    __syncthreads();
    for (int s = 1; s < SEQ; ++s) {
        if (t < NT) {
            float m = -3.4e38f; int bp = 0;
            #pragma unroll
            for (int i = 0; i < NT; ++i) {
                float v = sh_score[i] + sh_trans[i * NT + t];
                if (v > m) { m = v; bp = i; }
            }
            sh_hist[s - 1][t] = (unsigned char)bp;
            float best = m + sh_em[s][t];
            if (sh_mask[s]) sc = best;
        }
        __syncthreads();
        if (t < NT) sh_score[t] = sc;
        __syncthreads();
    }
    if (t == 0) {
        float bb = -3.4e38f; int tag = 0;
        for (int j = 0; j < NT; ++j) {
            float v = sh_score[j] + end_t[j];
            if (v > bb) { bb = v; tag = j; }
        }
        for (int pos = SEQ - 1; pos >= 1; --pos) {
            sh_tags[pos] = (unsigned char)tag;
            if (sh_mask[pos]) tag = sh_hist[pos - 1][tag];
        }
        sh_tags[0] = (unsigned char)tag;
    }
    __syncthreads();
    for (int idx = t; idx < SEQ; idx += 64) {
        out[b * SEQ + idx] = sh_mask[idx] ? (int)sh_tags[idx] : 0;
    }
}

extern "C" void kernel_launch(void* const* d_in, const int* in_sizes, int n_in,
                              void* d_out, int out_size, void* d_ws, size_t ws_size,
                              hipStream_t stream) {
    const int*   ids  = (const int*)d_in[0];
    const void*  mask = d_in[1];
    const float* emb  = (const float*)d_in[2];
    const float* Wihf = (const float*)d_in[3];
    const float* Whhf = (const float*)d_in[4];
    const float* bfv  = (const float*)d_in[5];
    const float* Wihb = (const float*)d_in[6];
    const float* Whhb = (const float*)d_in[7];
    const float* bbv  = (const float*)d_in[8];
    const float* Wout = (const float*)d_in[9];
    const float* bout = (const float*)d_in[10];
    const float* st   = (const float*)d_in[11];
    const float* en   = (const float*)d_in[12];
    const float* tr   = (const float*)d_in[13];
    int* out = (int*)d_out;

    char* ws = (char*)d_ws;
    float* table = (float*)ws;                                       // 245,760,000 B
    float* emp   = (float*)(ws + 245760000);                         //   4,718,592 B
    float* hx    = (float*)(ws + 245760000 + 4718592);               //     524,288 B
    int*   tags  = (int*)(ws + 245760000 + 4718592 + 524288);        //       2,048 B
    int*   flag  = (int*)(ws + 245760000 + 4718592 + 524288 + 2048); //           4 B

    k_detect<<<1, 128, 0, stream>>>((const unsigned char*)mask, flag);
    dim3 g1(32, 469);
    k_table_gemm<<<g1, 256, 0, stream>>>(emb, Wihf, Wihb, bfv, bbv, table);
    k_lstm_cl<<<256, 512, 0, stream>>>(ids, Whhf, Whhb, table, Wout, emp, hx, tags);
    k_viterbi<<<128, 64, 0, stream>>>(emp, bout, st, en, tr, mask, flag, out);
}

// Round 16
// 3422.315 us; speedup vs baseline: 1.5712x; 1.1282x over previous
//
#include <hip/hip_runtime.h>
#include <hip/hip_bf16.h>

#define SEQ   512
#define BATCH 128
#define VOCAB 30000
#define EDIM  256
#define HDIM  256
#define NT    9

// ---------------- K0b: detect mask storage dtype ----------------
__global__ void k_detect(const unsigned char* __restrict__ m, int* __restrict__ flag) {
    __shared__ int ok_sh;
    if (threadIdx.x == 0) ok_sh = 1;
    __syncthreads();
    int b = threadIdx.x;  // 128 threads, one row each
    const uint4* row = (const uint4*)(m + b * SEQ);
    int ok = 1, prev = 1;
    for (int i = 0; i < SEQ / 16; ++i) {
        uint4 v = row[i];
        unsigned w[4] = {v.x, v.y, v.z, v.w};
        #pragma unroll
        for (int wi = 0; wi < 4; ++wi) {
            #pragma unroll
            for (int j = 0; j < 4; ++j) {
                int byte = (w[wi] >> (8 * j)) & 255;
                if (byte > 1 || byte > prev) ok = 0;
                prev = byte;
            }
        }
    }
    if (!ok) atomicAnd(&ok_sh, 0);
    __syncthreads();
    if (threadIdx.x == 0) *flag = ok_sh;
}

// ---------------- K1: table[v][n] = embed[v] . Wcat[n] + bias[n] ----------------
__global__ __launch_bounds__(256) void k_table_gemm(
    const float* __restrict__ emb, const float* __restrict__ Wf,
    const float* __restrict__ Wb, const float* __restrict__ bf,
    const float* __restrict__ bb, float* __restrict__ table) {
    __shared__ __align__(16) float As[64][68];  // [k][m]
    __shared__ __align__(16) float Bs[64][68];  // [k][n]
    int t  = threadIdx.x;
    int tx = t & 15, ty = t >> 4;
    int n0 = blockIdx.x * 64;
    int v0 = blockIdx.y * 64;
    float acc[4][4] = {};
    for (int kc = 0; kc < 4; ++kc) {
        #pragma unroll
        for (int rr = 0; rr < 4; ++rr) {
            int slot = t + rr * 256;
            int m = slot >> 4, kq = slot & 15;
            int v = v0 + m;
            float4 a = (v < VOCAB)
                ? *(const float4*)&emb[v * EDIM + kc * 64 + kq * 4]
                : make_float4(0.f, 0.f, 0.f, 0.f);
            As[kq * 4 + 0][m] = a.x; As[kq * 4 + 1][m] = a.y;
            As[kq * 4 + 2][m] = a.z; As[kq * 4 + 3][m] = a.w;
            int n = n0 + m;
            const float* Wrow = (n < 1024) ? &Wf[n * 256] : &Wb[(n - 1024) * 256];
            float4 bvec = *(const float4*)&Wrow[kc * 64 + kq * 4];
            Bs[kq * 4 + 0][m] = bvec.x; Bs[kq * 4 + 1][m] = bvec.y;
            Bs[kq * 4 + 2][m] = bvec.z; Bs[kq * 4 + 3][m] = bvec.w;
        }
        __syncthreads();
        #pragma unroll
        for (int k = 0; k < 64; ++k) {
            float4 a = *(const float4*)&As[k][ty * 4];
            float4 b = *(const float4*)&Bs[k][tx * 4];
            acc[0][0] += a.x * b.x; acc[0][1] += a.x * b.y; acc[0][2] += a.x * b.z; acc[0][3] += a.x * b.w;
            acc[1][0] += a.y * b.x; acc[1][1] += a.y * b.y; acc[1][2] += a.y * b.z; acc[1][3] += a.y * b.w;
            acc[2][0] += a.z * b.x; acc[2][1] += a.z * b.y; acc[2][2] += a.z * b.z; acc[2][3] += a.z * b.w;
            acc[3][0] += a.w * b.x; acc[3][1] += a.w * b.y; acc[3][2] += a.w * b.z; acc[3][3] += a.w * b.w;
        }
        __syncthreads();
    }
    int n = n0 + tx * 4;
    const float* bi = (n < 1024) ? &bf[n] : &bb[n - 1024];
    float4 bias = *(const float4*)bi;
    #pragma unroll
    for (int i = 0; i < 4; ++i) {
        int v = v0 + ty * 4 + i;
        if (v < VOCAB) {
            float4 o;
            o.x = acc[i][0] + bias.x; o.y = acc[i][1] + bias.y;
            o.z = acc[i][2] + bias.z; o.w = acc[i][3] + bias.w;
            *(float4*)&table[(size_t)v * 2048 + n] = o;
        }
    }
}

// ---------------- K2: clustered LSTM, 2 blocks/CU, full-reg W ----------------
// 512 blocks x 512 threads, 2 blocks/CU (16 waves/CU) for stall overlap.
// cluster = bid>>3 (64), myd = bid&7 (dim chunk). dir = cluster&1,
// quad = cluster>>1: cluster handles batches quad*4..+3 of direction dir.
// Block owns dims [myd*32, myd*32+32) = 128 gate rows x 4 batches.
// Per-thread (r15-proven shape): g = t>>4 owns rows 4g..4g+3; kc = t&15 owns
// k4 in {kc,kc+16,kc+32,kc+48}; ALL W in 16 float4 regs (64 VGPR, no LDS W).
// a[16] tiles m = r*4+b. Butterfly: 4-stage thinning (strides 1,2 DPP;
// 4 shfl; 8 DPP row_ror:8); lane kc ends with tile
// ((kc&1)<<3)|((kc&2)<<1)|((kc&4)>>1)|((kc&8)>>3)  -> r = tile>>2, b = tile&3.
// sh_g[4][132] pad -> conflict-free. Exchange protocol identical to r9-r15:
// relaxed agent atomics -> L3, per-wave vmcnt(0), LDS ctr (2 nonlin waves) ->
// t0 publishes monotonic tag, 2-slot ring; wave wv polls+copies peer wv.
// Emission: blocks myd<4 emit batch quad*4+myd from h_em stash.
// Deadlock-safe without co-residency: cluster blocks are bid-contiguous.
#define DPPXOR(dst, src, CTRL) { \
    int _i = __float_as_int(src); \
    int _r = __builtin_amdgcn_update_dpp(_i, _i, (CTRL), 0xF, 0xF, false); \
    dst = __int_as_float(_r); }

__global__ __attribute__((amdgpu_flat_work_group_size(512, 512), amdgpu_waves_per_eu(4, 4)))
void k_lstm_cl(
    const int* __restrict__ ids, const float* __restrict__ Whhf,
    const float* __restrict__ Whhb, const float* __restrict__ table,
    const float* __restrict__ Wout, float* __restrict__ emp,
    float* hx, int* tagbuf) {
    __shared__ float h_cur[4][256];            // 4 KB linear
    __shared__ float h_em[256];                // 1 KB stash (emitted batch)
    __shared__ float sh_g[4][132];             // gates [batch][gate*32+dim], pad
    __shared__ float wout_s[NT][257];
    __shared__ int   sh_ctr;

    const int t   = threadIdx.x;
    const int bid = blockIdx.x;
    const int cluster = bid >> 3;              // 0..63
    const int myd = bid & 7;                   // dim chunk
    const int dir = cluster & 1;
    const int quad = cluster >> 1;             // 0..31
    const int gbatch = quad * 4 + myd;         // emitted batch (if myd<4)

    const int lane = t & 63;
    const int wv   = t >> 6;                   // 0..7
    const int g    = t >> 4;                   // row-group 0..31
    const int kc   = t & 15;                   // k lane 0..15

    const int nb = (t >> 5) & 3;               // nonlin batch (t<128)
    const int nd = t & 31;                     // nonlin dim-in-chunk

    const int em = t - 256;                    // emission map (256<=t<400)
    const int etg = em >> 4, el = em & 15;

    const float* Whh = dir ? Whhb : Whhf;

    if (t == 0) sh_ctr = 0;
    for (int idx = t; idx < NT * 256; idx += 512)
        wout_s[idx >> 8][idx & 255] = Wout[(idx >> 8) * 512 + dir * 256 + (idx & 255)];
    for (int idx = t; idx < 1024; idx += 512)
        h_cur[idx >> 8][idx & 255] = 0.f;
    float c_state = 0.f;

    // FULL register-resident W: rows 4g..4g+3, 4 float4 chunks each (64 VGPR)
    float4 w0_0, w0_1, w0_2, w0_3, w1_0, w1_1, w1_2, w1_3;
    float4 w2_0, w2_1, w2_2, w2_3, w3_0, w3_1, w3_2, w3_3;
    {
        int lr0 = 4 * g, lr1 = 4 * g + 1, lr2 = 4 * g + 2, lr3 = 4 * g + 3;
        int gr0 = (lr0 >> 5) * 256 + myd * 32 + (lr0 & 31);
        int gr1 = (lr1 >> 5) * 256 + myd * 32 + (lr1 & 31);
        int gr2 = (lr2 >> 5) * 256 + myd * 32 + (lr2 & 31);
        int gr3 = (lr3 >> 5) * 256 + myd * 32 + (lr3 & 31);
        const float4* wp0 = (const float4*)(Whh + (size_t)gr0 * 256);
        const float4* wp1 = (const float4*)(Whh + (size_t)gr1 * 256);
        const float4* wp2 = (const float4*)(Whh + (size_t)gr2 * 256);
        const float4* wp3 = (const float4*)(Whh + (size_t)gr3 * 256);
        w0_0 = wp0[kc]; w0_1 = wp0[kc + 16]; w0_2 = wp0[kc + 32]; w0_3 = wp0[kc + 48];
        w1_0 = wp1[kc]; w1_1 = wp1[kc + 16]; w1_2 = wp1[kc + 32]; w1_3 = wp1[kc + 48];
        w2_0 = wp2[kc]; w2_1 = wp2[kc + 16]; w2_2 = wp2[kc + 32]; w2_3 = wp2[kc + 48];
        w3_0 = wp3[kc]; w3_1 = wp3[kc + 16]; w3_2 = wp3[kc + 32]; w3_3 = wp3[kc + 48];
    }
    __syncthreads();

    // xg prefetch for it=0 (nonlin threads t<128 hold i,f,g,o in regs)
    float xi = 0.f, xf = 0.f, xq = 0.f, xo = 0.f;
    if (t < 128) {
        int s0 = dir ? SEQ - 1 : 0;
        int id = ids[(quad * 4 + nb) * SEQ + s0];
        const float* tb = table + (size_t)id * 2048 + dir * 1024;
        int base = myd * 32 + nd;
        xi = tb[base]; xf = tb[256 + base]; xq = tb[512 + base]; xo = tb[768 + base];
    }

    #pragma unroll 1
    for (int it = 0; it < SEQ; ++it) {
        // stash emitted batch's h_{it-1} + dot
        if (myd < 4 && t < 256) h_em[t] = h_cur[myd][t];

        float a[16];
        #pragma unroll
        for (int m = 0; m < 16; ++m) a[m] = 0.f;

        #define DOTJ(J, W0, W1, W2, W3) { \
            const int off = 4 * (kc + 16 * (J)); \
            _Pragma("unroll") \
            for (int b = 0; b < 4; ++b) { \
                float4 hv = *(const float4*)(&h_cur[b][0] + off); \
                a[b]      += W0.x*hv.x + W0.y*hv.y + W0.z*hv.z + W0.w*hv.w; \
                a[4 + b]  += W1.x*hv.x + W1.y*hv.y + W1.z*hv.z + W1.w*hv.w; \
                a[8 + b]  += W2.x*hv.x + W2.y*hv.y + W2.z*hv.z + W2.w*hv.w; \
                a[12 + b] += W3.x*hv.x + W3.y*hv.y + W3.z*hv.z + W3.w*hv.w; } }
        DOTJ(0, w0_0, w1_0, w2_0, w3_0)
        DOTJ(1, w0_1, w1_1, w2_1, w3_1)
        DOTJ(2, w0_2, w1_2, w2_2, w3_2)
        DOTJ(3, w0_3, w1_3, w2_3, w3_3)
        #undef DOTJ

        // 4-stage thinning butterfly over 16 kc-lanes.
        #pragma unroll
        for (int m = 0; m < 8; ++m) {           // stride 1: quad_perm [1,0,3,2]
            int bit = kc & 1;
            float sent = bit ? a[m] : a[m + 8];
            float recv; DPPXOR(recv, sent, 0xB1)
            a[m] = (bit ? a[m + 8] : a[m]) + recv;
        }
        #pragma unroll
        for (int m = 0; m < 4; ++m) {           // stride 2: quad_perm [2,3,0,1]
            int bit = kc & 2;
            float sent = bit ? a[m] : a[m + 4];
            float recv; DPPXOR(recv, sent, 0x4E)
            a[m] = (bit ? a[m + 4] : a[m]) + recv;
        }
        #pragma unroll
        for (int m = 0; m < 2; ++m) {           // stride 4: ds shuffle
            int bit = kc & 4;
            float sent = bit ? a[m] : a[m + 2];
            float recv = __shfl_xor(sent, 4);
            a[m] = (bit ? a[m + 2] : a[m]) + recv;
        }
        {                                       // stride 8: row_ror:8
            int bit = kc & 8;
            float sent = bit ? a[0] : a[1];
            float recv; DPPXOR(recv, sent, 0x128)
            a[0] = (bit ? a[1] : a[0]) + recv;
        }
        {
            // lane kc holds tile = bitrev4(kc): r = tile>>2, b = tile&3
            int tile = ((kc & 1) << 3) | ((kc & 2) << 1) | ((kc & 4) >> 1) | ((kc & 8) >> 3);
            sh_g[tile & 3][4 * g + (tile >> 2)] = a[0];
        }
        __syncthreads();   // BARRIER A: gates ready, h_cur reads done, h_em ready

        const int p = it & 1;
        float* hxp = hx + (size_t)p * 65536 + (size_t)cluster * 1024;
        int* tags = tagbuf + p * 512 + cluster * 8;

        if (t < 128) {
            // nonlin + publish (waves 0-1)
            float iv = sh_g[nb][nd]      + xi;
            float fv = sh_g[nb][32 + nd] + xf;
            float gv = sh_g[nb][64 + nd] + xq;
            float ov = sh_g[nb][96 + nd] + xo;
            float si = 1.f / (1.f + expf(-iv));
            float sf = 1.f / (1.f + expf(-fv));
            float so = 1.f / (1.f + expf(-ov));
            float tg = tanhf(gv);
            c_state = sf * c_state + si * tg;
            float hh = so * tanhf(c_state);
            int dl = myd * 32 + nd;
            h_cur[nb][dl] = hh;
            __hip_atomic_store(&hxp[nb * 256 + dl], hh,
                               __ATOMIC_RELAXED, __HIP_MEMORY_SCOPE_AGENT);
            asm volatile("s_waitcnt vmcnt(0)" ::: "memory");
            if (lane == 0) atomicAdd(&sh_ctr, 1);
            if (t == 0) {
                while (__hip_atomic_load(&sh_ctr, __ATOMIC_RELAXED,
                                         __HIP_MEMORY_SCOPE_WORKGROUP) < 2 * (it + 1)) {}
                __hip_atomic_store(&tags[myd], it,
                                   __ATOMIC_RELAXED, __HIP_MEMORY_SCOPE_AGENT);
            }
            // xg prefetch for it+1 (completes during next dot)
            if (it < SEQ - 1) {
                int sn = dir ? (SEQ - 2 - it) : (it + 1);
                int id = ids[(quad * 4 + nb) * SEQ + sn];
                const float* tb = table + (size_t)id * 2048 + dir * 1024;
                int base = myd * 32 + nd;
                xi = tb[base]; xf = tb[256 + base]; xq = tb[512 + base]; xo = tb[768 + base];
            }
        } else if (em >= 0 && em < 144 && myd < 4) {
            // emission for h_{it-1} from linear stash
            if (it > 0) {
                int sp = dir ? (SEQ - it) : (it - 1);
                float pe = 0.f;
                #pragma unroll
                for (int j = 0; j < 16; ++j)
                    pe += wout_s[etg][el + 16 * j] * h_em[el + 16 * j];
                pe += __shfl_xor(pe, 1); pe += __shfl_xor(pe, 2);
                pe += __shfl_xor(pe, 4); pe += __shfl_xor(pe, 8);
                if (el == 0)
                    emp[(((size_t)(dir * BATCH) + gbatch) * SEQ + sp) * NT + etg] = pe;
            }
        }

        // copy duty: wave wv polls + copies peer wv (skip own chunk)
        if (wv != myd) {
            while (__hip_atomic_load(&tags[wv], __ATOMIC_RELAXED,
                                     __HIP_MEMORY_SCOPE_AGENT) != it)
                __builtin_amdgcn_s_sleep(1);
            #pragma unroll
            for (int rep = 0; rep < 2; ++rep) {
                int idx = rep * 64 + lane;
                int b2 = idx >> 5, nd2 = idx & 31;
                float vv = __hip_atomic_load(&hxp[b2 * 256 + wv * 32 + nd2],
                                             __ATOMIC_RELAXED, __HIP_MEMORY_SCOPE_AGENT);
                h_cur[b2][wv * 32 + nd2] = vv;
            }
        }
        __syncthreads();   // BARRIER B: h_cur = full h_it
    }

    // final emission for h_{511}
    if (myd < 4 && t < 256) h_em[t] = h_cur[myd][t];
    __syncthreads();
    if (myd < 4 && t < 144) {
        int etg2 = t >> 4, el2 = t & 15;
        int sp = dir ? 0 : (SEQ - 1);
        float pe = 0.f;
        #pragma unroll
        for (int j = 0; j < 16; ++j)
            pe += wout_s[etg2][el2 + 16 * j] * h_em[el2 + 16 * j];
        pe += __shfl_xor(pe, 1); pe += __shfl_xor(pe, 2);
        pe += __shfl_xor(pe, 4); pe += __shfl_xor(pe, 8);
        if (el2 == 0)
            emp[(((size_t)(dir * BATCH) + gbatch) * SEQ + sp) * NT + etg2] = pe;
    }
}

// ---------------- K3: Viterbi decode per batch ----------------
__global__ __launch_bounds__(64) void k_viterbi(
    const float* __restrict__ emp, const float* __restrict__ b_out,
    const float* __restrict__ start_t, const float* __restrict__ end_t,
    const float* __restrict__ trans, const void* __restrict__ maskp,
    const int* __restrict__ mask_is_bool, int* __restrict__ out) {
    __shared__ float sh_em[SEQ][NT];
    __shared__ float sh_score[NT];
    __shared__ float sh_trans[NT * NT];
    __shared__ unsigned char sh_mask[SEQ];
    __shared__ unsigned char sh_hist[SEQ - 1][NT];
    __shared__ unsigned char sh_tags[SEQ];
    int b = blockIdx.x;
    int t = threadIdx.x;
    int isb = *mask_is_bool;
    for (int idx = t; idx < SEQ * NT; idx += 64) {
        int s = idx / NT, tg = idx % NT;
        sh_em[s][tg] = emp[((size_t)b * SEQ + s) * NT + tg]
                     + emp[(((size_t)BATCH + b) * SEQ + s) * NT + tg]
                     + b_out[tg];
    }
    if (isb) {
        const unsigned char* m8 = (const unsigned char*)maskp;
        for (int idx = t; idx < SEQ; idx += 64) sh_mask[idx] = m8[b * SEQ + idx];
    } else {
        const int* m32 = (const int*)maskp;
        for (int idx = t; idx < SEQ; idx += 64) sh_mask[idx] = (unsigned char)(m32[b * SEQ + idx] != 0);
    }
    for (int idx = t; idx < NT * NT; idx += 64) sh_trans[idx] = trans[idx];
    __syncthreads();
    float sc = 0.f;
    if (t < NT) { sc = start_t[t] + sh_em[0][t]; sh_score[t] = sc; }
    __syncthreads();
    for (int s = 1; s < SEQ; ++s) {
        if (t < NT) {
            float m = -3.4e38f; int bp = 0;
            #pragma unroll
            for (int i = 0; i < NT; ++i) {
                float v = sh_score[i] + sh_trans[i * NT + t];
                if (v > m) { m = v; bp = i; }
            }
            sh_hist[s - 1][t] = (unsigned char)bp;
            float best = m + sh_em[s][t];
            if (sh_mask[s]) sc = best;
        }
        __syncthreads();
        if (t < NT) sh_score[t] = sc;
        __syncthreads();
    }
    if (t == 0) {
        float bb = -3.4e38f; int tag = 0;
        for (int j = 0; j < NT; ++j) {
            float v = sh_score[j] + end_t[j];
            if (v > bb) { bb = v; tag = j; }
        }
        for (int pos = SEQ - 1; pos >= 1; --pos) {
            sh_tags[pos] = (unsigned char)tag;
            if (sh_mask[pos]) tag = sh_hist[pos - 1][tag];
        }
        sh_tags[0] = (unsigned char)tag;
    }
    __syncthreads();
    for (int idx = t; idx < SEQ; idx += 64) {
        out[b * SEQ + idx] = sh_mask[idx] ? (int)sh_tags[idx] : 0;
    }
}

extern "C" void kernel_launch(void* const* d_in, const int* in_sizes, int n_in,
                              void* d_out, int out_size, void* d_ws, size_t ws_size,
                              hipStream_t stream) {
    const int*   ids  = (const int*)d_in[0];
    const void*  mask = d_in[1];
    const float* emb  = (const float*)d_in[2];
    const float* Wihf = (const float*)d_in[3];
    const float* Whhf = (const float*)d_in[4];
    const float* bfv  = (const float*)d_in[5];
    const float* Wihb = (const float*)d_in[6];
    const float* Whhb = (const float*)d_in[7];
    const float* bbv  = (const float*)d_in[8];
    const float* Wout = (const float*)d_in[9];
    const float* bout = (const float*)d_in[10];
    const float* st   = (const float*)d_in[11];
    const float* en   = (const float*)d_in[12];
    const float* tr   = (const float*)d_in[13];
    int* out = (int*)d_out;

    char* ws = (char*)d_ws;
    float* table = (float*)ws;                                       // 245,760,000 B
    float* emp   = (float*)(ws + 245760000);                         //   4,718,592 B
    float* hx    = (float*)(ws + 245760000 + 4718592);               //     524,288 B
    int*   tags  = (int*)(ws + 245760000 + 4718592 + 524288);        //       4,096 B
    int*   flag  = (int*)(ws + 245760000 + 4718592 + 524288 + 4096); //           4 B

    k_detect<<<1, 128, 0, stream>>>((const unsigned char*)mask, flag);
    dim3 g1(32, 469);
    k_table_gemm<<<g1, 256, 0, stream>>>(emb, Wihf, Wihb, bfv, bbv, table);
    k_lstm_cl<<<512, 512, 0, stream>>>(ids, Whhf, Whhb, table, Wout, emp, hx, tags);
    k_viterbi<<<128, 64, 0, stream>>>(emp, bout, st, en, tr, mask, flag, out);
}